// Round 18
// baseline (34.629 us; speedup 1.0000x reference)
//
#include <hip/hip_runtime.h>

#define B_SZ 1024
#define F_SZ 512
#define NK   50
#define KD   5
#define C_SZ 250              // NK*KD
#define OUTW 562              // F_SZ + NK
#define PLANE (C_SZ * B_SZ)   // SoA M plane: [col c=k*5+d][row], 256000 floats
#define KS   4                // k-splits (512 gemm blocks, 2.5 blocks/CU)
#define NT   16               // 16 row-tiles of 64
#define TILE 64
#define NPAIRS 136            // NT*(NT+1)/2 unordered tile pairs
#define PART_ELEMS (NK * NT * B_SZ)   // 819200 floats
#define LOG2E 1.44269504088896340736f

// ---------------------------------------------------------------------------
// K1: fused GEMM + copy. grid 640 x 256. Round-18 change (single-variable vs
// r17): x loads widened to UNIFORM float4 -> s_load_dwordx4. r17's loop
// issued 1024 narrow 4B s_loads/block (stride 2KB, all L2 misses at ~200cy) —
// the scalar pipe was the latency wall TLP couldn't fix (r17: KS 2->4 bought
// only 1.2us). Now: per 4-f chunk = 8 wide scalar loads + 4 coalesced vector
// loads + 32 FMA; SMEM op count /4 at same bytes.
//  blocks [0,512):   rt = blk&127 (8 rows), ks = blk>>7 (128 f each).
//  blocks [512,640): copy x rows into out (float2), 8 rows/block.
// ---------------------------------------------------------------------------
__global__ __launch_bounds__(256) void gemm_copy_kernel(const float* __restrict__ x,
                                                        const float* __restrict__ T,
                                                        float* __restrict__ ws2,
                                                        float* __restrict__ out,
                                                        int zero_feat) {
    const int t = threadIdx.x;

    if (blockIdx.x >= 512) {                 // ---- copy path
        const int b = blockIdx.x - 512;      // 0..127
#pragma unroll
        for (int r = 0; r < 8; ++r) {
            const int row = b * 8 + r;
            const float2* src = (const float2*)(x + (size_t)row * F_SZ);
            float2* dst = (float2*)(out + (size_t)row * OUTW);
            dst[t] = src[t];
            if (zero_feat && t < NK) out[(size_t)row * OUTW + F_SZ + t] = 0.0f;
        }
        return;
    }

    // ---- gemm path
    const int rt = blockIdx.x & 127;         // 8-row tile
    const int ks = blockIdx.x >> 7;          // k-split (0..3)
    if (t >= C_SZ) return;                   // no __syncthreads in this path
    const int r0 = rt * 8;
    const int f0 = ks * 128;                 // multiple of 4 -> 16B-aligned x

    float acc[8] = {0.f, 0.f, 0.f, 0.f, 0.f, 0.f, 0.f, 0.f};
    const float* xp = x + (size_t)r0 * F_SZ + f0;     // block-uniform base
    const float* Tp = T + (size_t)f0 * C_SZ + t;

#pragma unroll 2
    for (int c = 0; c < 32; ++c) {           // 4-f chunks
        const int f = c * 4;
        float4 xr[8];                        // uniform -> s_load_dwordx4 (SGPRs)
#pragma unroll
        for (int r = 0; r < 8; ++r)
            xr[r] = *(const float4*)(xp + r * F_SZ + f);
        const float tv0 = Tp[(size_t)(f + 0) * C_SZ];   // coalesced vector loads
        const float tv1 = Tp[(size_t)(f + 1) * C_SZ];
        const float tv2 = Tp[(size_t)(f + 2) * C_SZ];
        const float tv3 = Tp[(size_t)(f + 3) * C_SZ];
#pragma unroll
        for (int r = 0; r < 8; ++r) {
            acc[r] += xr[r].x * tv0;
            acc[r] += xr[r].y * tv1;
            acc[r] += xr[r].z * tv2;
            acc[r] += xr[r].w * tv3;
        }
    }

    float* dst = ws2 + ((size_t)(ks * C_SZ + t)) * B_SZ + r0;   // 32B aligned
    float4 lo = make_float4(acc[0] * LOG2E, acc[1] * LOG2E,
                            acc[2] * LOG2E, acc[3] * LOG2E);
    float4 hi = make_float4(acc[4] * LOG2E, acc[5] * LOG2E,
                            acc[6] * LOG2E, acc[7] * LOG2E);
    ((float4*)dst)[0] = lo;
    ((float4*)dst)[1] = hi;
}

// ---------------------------------------------------------------------------
// K2: symmetric pairwise features (round-17 version, byte-identical).
// grid 6800 = 50 k x 136 tile pairs (ti<=tj); 256 threads.
// ---------------------------------------------------------------------------
template <bool ATOMIC>
__global__ __launch_bounds__(256) void pair_kernel(const float* __restrict__ ws2,
                                                   float* __restrict__ part,
                                                   float* __restrict__ out) {
    // ---- decode block id -> (k, ti, tj), all scalar-uniform
    const int bid = blockIdx.x;
    const int k = bid / NPAIRS;
    int p = bid - k * NPAIRS;
    int ti = 0;
    while (p >= NT - ti) { p -= NT - ti; ++ti; }
    const int tj = ti + p;

    const int t    = threadIdx.x;
    const int lane = t & 63;
    const int jq   = t >> 6;

    __shared__ __align__(16) float qi[KD][TILE];
    __shared__ __align__(16) float qj[KD][TILE];
    __shared__ float et[TILE][TILE + 1];     // padded: b32 access both ways
    __shared__ float rowp[4][TILE];
    __shared__ float colp[4][TILE];

    const float* pk = ws2 + (size_t)k * (KD * B_SZ);  // plane 0, cols k*5..

    if (t < TILE) {                          // stage tile ti (coalesced SoA)
#pragma unroll
        for (int d = 0; d < KD; ++d) {
            const int row = ti * TILE + t;
            float v = 0.0f;
#pragma unroll
            for (int pl = 0; pl < KS; ++pl)
                v += pk[(size_t)pl * PLANE + d * B_SZ + row];
            qi[d][t] = v;
        }
    } else if (t < 2 * TILE) {               // stage tile tj
        const int l = t - TILE;
#pragma unroll
        for (int d = 0; d < KD; ++d) {
            const int row = tj * TILE + l;
            float v = 0.0f;
#pragma unroll
            for (int pl = 0; pl < KS; ++pl)
                v += pk[(size_t)pl * PLANE + d * B_SZ + row];
            qj[d][l] = v;
        }
    }
    __syncthreads();

    // ---- pass 1: 16 pairs/thread (i = lane, j = jq*16 + 0..15)
    float m0 = qi[0][lane], m1 = qi[1][lane], m2 = qi[2][lane],
          m3 = qi[3][lane], m4 = qi[4][lane];
    float acc = 0.0f;
#pragma unroll
    for (int c4 = 0; c4 < 4; ++c4) {
        const int j0 = jq * 16 + c4 * 4;
        const float4 c0 = *(const float4*)&qj[0][j0];   // broadcast b128
        const float4 c1 = *(const float4*)&qj[1][j0];
        const float4 c2 = *(const float4*)&qj[2][j0];
        const float4 c3 = *(const float4*)&qj[3][j0];
        const float4 c4_ = *(const float4*)&qj[4][j0];
#define PAIR_ONE(C, JOFF)                                                        \
        {                                                                        \
            const float s = __builtin_fabsf(m0 - c0.C)                           \
                          + __builtin_fabsf(m1 - c1.C)                           \
                          + __builtin_fabsf(m2 - c2.C)                           \
                          + __builtin_fabsf(m3 - c3.C)                           \
                          + __builtin_fabsf(m4 - c4_.C);                         \
            const float e = __builtin_amdgcn_exp2f(-s);                          \
            acc += e;                                                            \
            et[j0 + JOFF][lane] = e;                                             \
        }
        PAIR_ONE(x, 0) PAIR_ONE(y, 1) PAIR_ONE(z, 2) PAIR_ONE(w, 3)
#undef PAIR_ONE
    }
    rowp[jq][lane] = acc;
    __syncthreads();

    // ---- pass 2: column sums (rows of et), off-diagonal only
    if (ti != tj) {
        float csum = 0.0f;
#pragma unroll
        for (int e = 0; e < 16; ++e) csum += et[lane][jq * 16 + e];
        colp[jq][lane] = csum;
    }

    // ---- row partial: rows of tile ti, source tile tj
    if (t < TILE) {
        const float r = rowp[0][t] + rowp[1][t] + rowp[2][t] + rowp[3][t];
        const int row = ti * TILE + t;
        if (ATOMIC) atomicAdd(&out[(size_t)row * OUTW + F_SZ + k], r);
        else        part[((size_t)(k * NT + tj)) * B_SZ + row] = r;
    }

    // ---- col partial: rows of tile tj, source tile ti
    if (ti != tj) {
        __syncthreads();
        if (t < TILE) {
            const float c = colp[0][t] + colp[1][t] + colp[2][t] + colp[3][t];
            const int row = tj * TILE + t;
            if (ATOMIC) atomicAdd(&out[(size_t)row * OUTW + F_SZ + k], c);
            else        part[((size_t)(k * NT + ti)) * B_SZ + row] = c;
        }
    }
}

// ---------------------------------------------------------------------------
// K3: fold the 16 tile-source partials into out. grid 200 x 256.
// Reads coalesced (lanes contiguous in row); L2-resident.
// ---------------------------------------------------------------------------
__global__ __launch_bounds__(256) void reduce_kernel(const float* __restrict__ part,
                                                     float* __restrict__ out) {
    const int k = blockIdx.x >> 2;
    const int i = ((blockIdx.x & 3) << 8) | threadIdx.x;
    float s = 0.0f;
#pragma unroll
    for (int sp = 0; sp < NT; ++sp)
        s += part[((size_t)(k * NT + sp)) * B_SZ + i];
    out[(size_t)i * OUTW + F_SZ + k] = s;
}

// ---------------------------------------------------------------------------
extern "C" void kernel_launch(void* const* d_in, const int* in_sizes, int n_in,
                              void* d_out, int out_size, void* d_ws, size_t ws_size,
                              hipStream_t stream) {
    const float* x = (const float*)d_in[0];   // [1024, 512]
    const float* T = (const float*)d_in[1];   // [512, 250]
    float* out = (float*)d_out;               // [1024, 562]
    float* ws2 = (float*)d_ws;                // KS SoA planes [250][1024]
    float* part = ws2 + (size_t)KS * PLANE;   // [50][16][1024]

    const size_t need = ((size_t)KS * PLANE + PART_ELEMS) * 4;   // 7.4 MB
    const int fast = (ws_size >= need);

    gemm_copy_kernel<<<640, 256, 0, stream>>>(x, T, ws2, out, fast ? 0 : 1);

    if (fast) {
        pair_kernel<false><<<NK * NPAIRS, 256, 0, stream>>>(ws2, part, out);
        reduce_kernel<<<200, 256, 0, stream>>>(part, out);
    } else {
        pair_kernel<true><<<NK * NPAIRS, 256, 0, stream>>>(ws2, nullptr, out);
    }
}